// Round 11
// baseline (70.142 us; speedup 1.0000x reference)
//
#include <hip/hip_runtime.h>
#include <hip/hip_bf16.h>
#include <cstddef>

// Problem constants: N=100000, E=1600000
constexpr int HID  = 128;
constexpr int OUTW = 32;    // N_CHUNKS * STRU
constexpr int TOT  = 64;    // P outs + Q outs
constexpr int STRU = 4;
constexpr int NCH  = 8;
constexpr int RPAD = 132;   // padded fp32 row stride in LDS (128 + 4)

typedef short  bf16x8 __attribute__((ext_vector_type(8)));
typedef float  f32x4  __attribute__((ext_vector_type(4)));
typedef int    int4v  __attribute__((ext_vector_type(4)));
typedef unsigned short u16x8 __attribute__((ext_vector_type(8)));

__device__ __forceinline__ unsigned short f2bf(float f) {
    unsigned u = __builtin_bit_cast(unsigned, f);
    u += 0x7FFFu + ((u >> 16) & 1u);          // round-to-nearest-even
    return (unsigned short)(u >> 16);
}

__device__ __forceinline__ float dot4(float4 a, float4 b) {
    return a.x * b.x + a.y * b.y + a.z * b.z + a.w * b.w;
}

// bf16 dot of 8 pairs packed in int4v words, accumulated into sum
__device__ __forceinline__ float bfdot(int4v a, int4v b, float sum) {
#pragma unroll
    for (int w = 0; w < 4; ++w) {
        float alo = __builtin_bit_cast(float, (unsigned)(a[w] << 16));
        float ahi = __builtin_bit_cast(float, (unsigned)a[w] & 0xffff0000u);
        float blo = __builtin_bit_cast(float, (unsigned)(b[w] << 16));
        float bhi = __builtin_bit_cast(float, (unsigned)b[w] & 0xffff0000u);
        sum = fmaf(alo, blo, sum);
        sum = fmaf(ahi, bhi, sum);
    }
    return sum;
}

// ---------------------------------------------------------------------------
// Proj (MFMA): 64 nodes per 256-thread block.
//  - x tile staged via fully-coalesced float4 loads into padded LDS
//    (writes: 4-way bank alias on 8 instrs, negligible; fragment reads:
//    <=2-way, free) -- fixes the 16-row-scattered A-fragment load pattern
//    that held proj at ~half streaming BW.
//  - Weights converted fp32->bf16 fragment-ordered into LDS per block.
//  - Epilogue transpose buffer sPQ ALIASED over sX (sX reads done by then).
//    LDS total 50 KB -> 3 blocks/CU.
// ---------------------------------------------------------------------------
__global__ __launch_bounds__(256) void proj_mfma(
    const float* __restrict__ x,
    const float* __restrict__ Wq, const float* __restrict__ bq,
    const float* __restrict__ Wv, const float* __restrict__ bv,
    unsigned short* __restrict__ P,
    unsigned short* __restrict__ Q,
    int n_nodes)
{
    __shared__ unsigned short sW[TOT * HID];   // 16 KB, fragment-ordered
    __shared__ float sX[64 * RPAD];            // 33.8 KB, padded x tile

    const int tid  = threadIdx.x;
    const int wid  = tid >> 6;
    const int lane = tid & 63;
    const int lr   = lane & 15;   // A-row / C-col
    const int lg   = lane >> 4;   // k-group / C row-group
    const int base = blockIdx.x * 64;

    // ---- coalesced x -> LDS staging: 8 float4/thread, 1KB/wave-instr ----
    {
        const float4* xg = reinterpret_cast<const float4*>(x + (size_t)base * HID);
        const int rows   = (n_nodes - base < 64) ? (n_nodes - base) : 64;
        const int maxf4  = rows * 32;
#pragma unroll
        for (int j = 0; j < 8; ++j) {
            int g = tid + 256 * j;
            float4 v = make_float4(0.f, 0.f, 0.f, 0.f);
            if (g < maxf4) v = xg[g];
            int row = g >> 5, c4 = g & 31;
            *reinterpret_cast<float4*>(&sX[row * RPAD + c4 * 4]) = v;
        }
    }

    // ---- convert weights fp32 -> bf16 fragments in LDS (32 elems/thread) ----
#pragma unroll
    for (int g = 0; g < 4; ++g) {
        int f     = tid * 8 + g * 2048;
        int lane6 = (f >> 3) & 63;
        int kc    = (f >> 9) & 3;
        int t     = f >> 11;
        int o     = t * 16 + (lane6 & 15);
        int k0    = kc * 32 + (lane6 >> 4) * 8;
        const float* wrow = (o < OUTW) ? (Wq + (size_t)o * HID)
                                       : (Wv + (size_t)(o - OUTW) * HID);
        f32x4 w0 = *reinterpret_cast<const f32x4*>(wrow + k0);
        f32x4 w1 = *reinterpret_cast<const f32x4*>(wrow + k0 + 4);
        u16x8 pk;
        pk[0] = f2bf(w0[0]); pk[1] = f2bf(w0[1]); pk[2] = f2bf(w0[2]); pk[3] = f2bf(w0[3]);
        pk[4] = f2bf(w1[0]); pk[5] = f2bf(w1[1]); pk[6] = f2bf(w1[2]); pk[7] = f2bf(w1[3]);
        *reinterpret_cast<u16x8*>(sW + f) = pk;
    }

    // ---- bias into accumulators ----
    f32x4 acc[4];
#pragma unroll
    for (int t = 0; t < 4; ++t) {
        float b = (t < 2) ? bq[t * 16 + lr] : bv[(t - 2) * 16 + lr];
        acc[t][0] = b; acc[t][1] = b; acc[t][2] = b; acc[t][3] = b;
    }

    __syncthreads();   // sX + sW ready

    // ---- MFMA: A-fragments read from padded LDS (<=2-way banks) ----
    const int xrow = wid * 16 + lr;
#pragma unroll
    for (int kc = 0; kc < 4; ++kc) {
        const float* xp = &sX[xrow * RPAD + kc * 32 + lg * 8];
        f32x4 f0 = *reinterpret_cast<const f32x4*>(xp);
        f32x4 f1 = *reinterpret_cast<const f32x4*>(xp + 4);
        bf16x8 a;
        a[0] = (short)f2bf(f0[0]); a[1] = (short)f2bf(f0[1]);
        a[2] = (short)f2bf(f0[2]); a[3] = (short)f2bf(f0[3]);
        a[4] = (short)f2bf(f1[0]); a[5] = (short)f2bf(f1[1]);
        a[6] = (short)f2bf(f1[2]); a[7] = (short)f2bf(f1[3]);
#pragma unroll
        for (int t = 0; t < 4; ++t) {
            bf16x8 bf = *reinterpret_cast<const bf16x8*>(
                sW + ((size_t)(t * 4 + kc) * 64 + lane) * 8);
            acc[t] = __builtin_amdgcn_mfma_f32_16x16x32_bf16(a, bf, acc[t], 0, 0, 0);
        }
    }

    __syncthreads();   // all sX reads complete -> safe to alias sPQ over sX

    unsigned short (*sPQ)[TOT + 8] =
        reinterpret_cast<unsigned short (*)[TOT + 8]>(sX);

    // ---- fragments -> LDS (2B stores, <=2-way alias: free) ----
    const int lrow = wid * 16 + lg * 4;
#pragma unroll
    for (int t = 0; t < 4; ++t)
#pragma unroll
        for (int j = 0; j < 4; ++j)
            sPQ[lrow + j][t * 16 + lr] = f2bf(acc[t][j]);
    __syncthreads();

    // ---- LDS -> global, coalesced: 4 threads/node, 32B each ----
    const int row  = tid >> 2;          // 0..63
    const int q    = tid & 3;           // 0,1 -> P halves; 2,3 -> Q halves
    const int node = base + row;
    if (node < n_nodes) {
        const int scol = q * 16;        // 0,16,32,48
        u16x8 v0 = *reinterpret_cast<const u16x8*>(&sPQ[row][scol]);
        u16x8 v1 = *reinterpret_cast<const u16x8*>(&sPQ[row][scol + 8]);
        unsigned short* dstbase = (q < 2) ? (P + (size_t)node * OUTW + q * 16)
                                          : (Q + (size_t)node * OUTW + (q - 2) * 16);
        u16x8* dst = reinterpret_cast<u16x8*>(dstbase);
        dst[0] = v0;
        dst[1] = v1;
    }
}

// ---------------------------------------------------------------------------
// Edge: proven R6 shape (1 edge/thread, 8x16B gathers, nt index/store).
// Fabric/L2-bound at ~46us -- R4/R7/R8 A/B showed deeper per-thread MLP
// does NOT help; do not revisit.
// ---------------------------------------------------------------------------
__global__ __launch_bounds__(256) void edge_bf16(
    const int* __restrict__ e,
    const unsigned short* __restrict__ P,
    const unsigned short* __restrict__ Q,
    const float* __restrict__ ratio_p,
    float* __restrict__ out, int E_)
{
    int i = blockIdx.x * blockDim.x + threadIdx.x;
    if (i >= E_) return;

    float scale = (1.0f - ratio_p[0]) * 0.5f;
    int e0 = __builtin_nontemporal_load(e + i);
    int e1 = __builtin_nontemporal_load(e + E_ + i);

    const int4v* p4 = reinterpret_cast<const int4v*>(P + (size_t)e0 * OUTW);
    const int4v* q4 = reinterpret_cast<const int4v*>(Q + (size_t)e1 * OUTW);

    int4v a[STRU], b[STRU];
#pragma unroll
    for (int s = 0; s < STRU; ++s) { a[s] = p4[s]; b[s] = q4[s]; }

#pragma unroll
    for (int s = 0; s < STRU; ++s) {
        float sum = bfdot(a[s], b[s], 0.f);
        float sig = 1.0f / (1.0f + __expf(-sum));
        float r   = sig * scale + 1.0f;
        __builtin_nontemporal_store(r, out + (size_t)s * E_ + i);
    }
}

// ---------------------------------------------------------------------------
// Fallback: fully fused per-edge (only if workspace too small).
// ---------------------------------------------------------------------------
__global__ __launch_bounds__(256) void fused_kernel(
    const float* __restrict__ x,
    const int* __restrict__ e,
    const float* __restrict__ ratio_p,
    const float* __restrict__ Wq, const float* __restrict__ bq,
    const float* __restrict__ Wv, const float* __restrict__ bv,
    float* __restrict__ out, int E_)
{
    int i = blockIdx.x * blockDim.x + threadIdx.x;
    if (i >= E_) return;

    float scale = (1.0f - ratio_p[0]) * 0.5f;
    int e0 = e[i];
    int e1 = e[E_ + i];

    const float4* __restrict__ xu  = reinterpret_cast<const float4*>(x + (size_t)e0 * HID);
    const float4* __restrict__ xv_ = reinterpret_cast<const float4*>(x + (size_t)e1 * HID);
    const float4* __restrict__ Wq4 = reinterpret_cast<const float4*>(Wq);
    const float4* __restrict__ Wv4 = reinterpret_cast<const float4*>(Wv);

#pragma unroll 1
    for (int s = 0; s < STRU; ++s) {
        float accP[NCH], accQ[NCH];
#pragma unroll
        for (int c = 0; c < NCH; ++c) { accP[c] = bq[s*NCH+c]; accQ[c] = bv[s*NCH+c]; }
        for (int kc = 0; kc < HID / 4; ++kc) {
            float4 u = xu[kc];
            float4 v = xv_[kc];
#pragma unroll
            for (int c = 0; c < NCH; ++c) {
                int o = s * NCH + c;
                accP[c] += dot4(u, Wq4[o * (HID / 4) + kc]);
                accQ[c] += dot4(v, Wv4[o * (HID / 4) + kc]);
            }
        }
        float sum = 0.0f;
#pragma unroll
        for (int c = 0; c < NCH; ++c) sum += accP[c] * accQ[c];
        float sig = 1.0f / (1.0f + __expf(-sum));
        out[(size_t)s * E_ + i] = sig * scale + 1.0f;
    }
}

extern "C" void kernel_launch(void* const* d_in, const int* in_sizes, int n_in,
                              void* d_out, int out_size, void* d_ws, size_t ws_size,
                              hipStream_t stream)
{
    const float* x     = (const float*)d_in[0];
    const int*   e     = (const int*)  d_in[1];
    const float* ratio = (const float*)d_in[2];
    const float* Wq    = (const float*)d_in[3];
    const float* bq    = (const float*)d_in[4];
    const float* Wv    = (const float*)d_in[5];
    const float* bv    = (const float*)d_in[6];
    float* out = (float*)d_out;

    int N_ = in_sizes[0] / HID;
    int E_ = in_sizes[1] / 2;

    // workspace: P (bf16 N_*32) | Q (bf16 N_*32)
    size_t need = (size_t)N_ * OUTW * 2 * sizeof(unsigned short);
    if (ws_size >= need) {
        unsigned short* P  = (unsigned short*)d_ws;
        unsigned short* Qb = P + (size_t)N_ * OUTW;

        proj_mfma<<<(N_ + 63) / 64, 256, 0, stream>>>(x, Wq, bq, Wv, bv, P, Qb, N_);
        edge_bf16<<<(E_ + 255) / 256, 256, 0, stream>>>(e, P, Qb, ratio, out, E_);
    } else {
        fused_kernel<<<(E_ + 255) / 256, 256, 0, stream>>>(x, e, ratio, Wq, bq, Wv, bv, out, E_);
    }
}

// Round 12
// 67.270 us; speedup vs baseline: 1.0427x; 1.0427x over previous
//
#include <hip/hip_runtime.h>
#include <hip/hip_bf16.h>
#include <cstddef>

// Problem constants: N=100000, E=1600000
constexpr int HID  = 128;
constexpr int OUTW = 32;    // N_CHUNKS * STRU
constexpr int TOT  = 64;    // P outs + Q outs
constexpr int STRU = 4;
constexpr int NCH  = 8;

typedef short  bf16x8 __attribute__((ext_vector_type(8)));
typedef float  f32x4  __attribute__((ext_vector_type(4)));
typedef int    int4v  __attribute__((ext_vector_type(4)));
typedef unsigned short u16x8 __attribute__((ext_vector_type(8)));

__device__ __forceinline__ unsigned short f2bf(float f) {
    unsigned u = __builtin_bit_cast(unsigned, f);
    u += 0x7FFFu + ((u >> 16) & 1u);          // round-to-nearest-even
    return (unsigned short)(u >> 16);
}

__device__ __forceinline__ float dot4(float4 a, float4 b) {
    return a.x * b.x + a.y * b.y + a.z * b.z + a.w * b.w;
}

// bf16 dot of 8 pairs packed in int4v words, accumulated into sum
__device__ __forceinline__ float bfdot(int4v a, int4v b, float sum) {
#pragma unroll
    for (int w = 0; w < 4; ++w) {
        float alo = __builtin_bit_cast(float, (unsigned)(a[w] << 16));
        float ahi = __builtin_bit_cast(float, (unsigned)a[w] & 0xffff0000u);
        float blo = __builtin_bit_cast(float, (unsigned)(b[w] << 16));
        float bhi = __builtin_bit_cast(float, (unsigned)b[w] & 0xffff0000u);
        sum = fmaf(alo, blo, sum);
        sum = fmaf(ahi, bhi, sum);
    }
    return sum;
}

// ---------------------------------------------------------------------------
// Proj (MFMA): R10 configuration -- measured best (67.3 us total).
// 2 node-tiles (2x64 nodes) per 256-thread block; ALL x loads for both tiles
// issued up-front (16 x 16B per thread outstanding); weights converted
// fp32->bf16 fragment-ordered into LDS once per block; padded-LDS transpose
// epilogue with coalesced 16B stores. LDS 25.2 KB.
// NOTE (R11 lesson): staging x through LDS with coalesced loads REGRESSED
// (70.1 us) -- direct scattered A-fragment loads are already L2/L3-absorbed.
// ---------------------------------------------------------------------------
__global__ __launch_bounds__(256) void proj_mfma(
    const float* __restrict__ x,
    const float* __restrict__ Wq, const float* __restrict__ bq,
    const float* __restrict__ Wv, const float* __restrict__ bv,
    unsigned short* __restrict__ P,
    unsigned short* __restrict__ Q,
    int n_nodes)
{
    __shared__ unsigned short sW[TOT * HID];      // 16 KB, fragment-ordered
    __shared__ unsigned short sPQ[64][TOT + 8];   // 9.2 KB transpose buffer

    const int tid  = threadIdx.x;
    const int wid  = tid >> 6;
    const int lane = tid & 63;
    const int lr   = lane & 15;   // A-row / C-col
    const int lg   = lane >> 4;   // k-group / C row-group

    const int bases[2] = { (int)blockIdx.x * 64,
                           (int)(blockIdx.x + gridDim.x) * 64 };

    // ---- issue ALL x loads for both tiles first (16 outstanding 16B) ----
    f32x4 xv[2][8];
#pragma unroll
    for (int it = 0; it < 2; ++it) {
        const int  arow = bases[it] + wid * 16 + lr;
        const bool aok  = arow < n_nodes;
        const float* ap = x + (size_t)arow * HID;
#pragma unroll
        for (int kc = 0; kc < 4; ++kc) {
            if (aok) {
                const f32x4* p = reinterpret_cast<const f32x4*>(ap + kc * 32 + lg * 8);
                xv[it][2 * kc + 0] = p[0];
                xv[it][2 * kc + 1] = p[1];
            } else {
                xv[it][2 * kc + 0] = (f32x4)0.f;
                xv[it][2 * kc + 1] = (f32x4)0.f;
            }
        }
    }

    // ---- convert weights fp32 -> bf16 fragments in LDS (32 elems/thread) ----
#pragma unroll
    for (int g = 0; g < 4; ++g) {
        int f     = tid * 8 + g * 2048;
        int lane6 = (f >> 3) & 63;
        int kc    = (f >> 9) & 3;
        int t     = f >> 11;
        int o     = t * 16 + (lane6 & 15);
        int k0    = kc * 32 + (lane6 >> 4) * 8;
        const float* wrow = (o < OUTW) ? (Wq + (size_t)o * HID)
                                       : (Wv + (size_t)(o - OUTW) * HID);
        f32x4 w0 = *reinterpret_cast<const f32x4*>(wrow + k0);
        f32x4 w1 = *reinterpret_cast<const f32x4*>(wrow + k0 + 4);
        u16x8 pk;
        pk[0] = f2bf(w0[0]); pk[1] = f2bf(w0[1]); pk[2] = f2bf(w0[2]); pk[3] = f2bf(w0[3]);
        pk[4] = f2bf(w1[0]); pk[5] = f2bf(w1[1]); pk[6] = f2bf(w1[2]); pk[7] = f2bf(w1[3]);
        *reinterpret_cast<u16x8*>(sW + f) = pk;
    }

    __syncthreads();   // sW ready

#pragma unroll
    for (int it = 0; it < 2; ++it) {
        const int base = bases[it];

        // ---- bias into accumulators ----
        f32x4 acc[4];
#pragma unroll
        for (int t = 0; t < 4; ++t) {
            float b = (t < 2) ? bq[t * 16 + lr] : bv[(t - 2) * 16 + lr];
            acc[t][0] = b; acc[t][1] = b; acc[t][2] = b; acc[t][3] = b;
        }

#pragma unroll
        for (int kc = 0; kc < 4; ++kc) {
            f32x4 f0 = xv[it][2 * kc + 0], f1 = xv[it][2 * kc + 1];
            bf16x8 a;
            a[0] = (short)f2bf(f0[0]); a[1] = (short)f2bf(f0[1]);
            a[2] = (short)f2bf(f0[2]); a[3] = (short)f2bf(f0[3]);
            a[4] = (short)f2bf(f1[0]); a[5] = (short)f2bf(f1[1]);
            a[6] = (short)f2bf(f1[2]); a[7] = (short)f2bf(f1[3]);
#pragma unroll
            for (int t = 0; t < 4; ++t) {
                bf16x8 bf = *reinterpret_cast<const bf16x8*>(
                    sW + ((size_t)(t * 4 + kc) * 64 + lane) * 8);
                acc[t] = __builtin_amdgcn_mfma_f32_16x16x32_bf16(a, bf, acc[t], 0, 0, 0);
            }
        }

        if (it) __syncthreads();   // previous tile's sPQ reads complete

        // ---- fragments -> LDS (2B stores, <=2-way alias: free) ----
        const int lrow = wid * 16 + lg * 4;
#pragma unroll
        for (int t = 0; t < 4; ++t)
#pragma unroll
            for (int j = 0; j < 4; ++j)
                sPQ[lrow + j][t * 16 + lr] = f2bf(acc[t][j]);
        __syncthreads();

        // ---- LDS -> global, coalesced: 4 threads/node, 32B each ----
        const int row  = tid >> 2;          // 0..63
        const int q    = tid & 3;           // 0,1 -> P halves; 2,3 -> Q halves
        const int node = base + row;
        if (node < n_nodes) {
            const int scol = q * 16;        // 0,16,32,48
            u16x8 v0 = *reinterpret_cast<const u16x8*>(&sPQ[row][scol]);
            u16x8 v1 = *reinterpret_cast<const u16x8*>(&sPQ[row][scol + 8]);
            unsigned short* dstbase = (q < 2) ? (P + (size_t)node * OUTW + q * 16)
                                              : (Q + (size_t)node * OUTW + (q - 2) * 16);
            u16x8* dst = reinterpret_cast<u16x8*>(dstbase);
            dst[0] = v0;
            dst[1] = v1;
        }
    }
}

// ---------------------------------------------------------------------------
// Edge: proven shape (1 edge/thread, 8x16B gathers, nt index/store).
// Fabric/L2-bound at ~46.5us (FETCH 145 MB, ~3.7 TB/s service). R4/R7/R8
// falsified the concurrency hypothesis three ways; do not revisit.
// ---------------------------------------------------------------------------
__global__ __launch_bounds__(256) void edge_bf16(
    const int* __restrict__ e,
    const unsigned short* __restrict__ P,
    const unsigned short* __restrict__ Q,
    const float* __restrict__ ratio_p,
    float* __restrict__ out, int E_)
{
    int i = blockIdx.x * blockDim.x + threadIdx.x;
    if (i >= E_) return;

    float scale = (1.0f - ratio_p[0]) * 0.5f;
    int e0 = __builtin_nontemporal_load(e + i);
    int e1 = __builtin_nontemporal_load(e + E_ + i);

    const int4v* p4 = reinterpret_cast<const int4v*>(P + (size_t)e0 * OUTW);
    const int4v* q4 = reinterpret_cast<const int4v*>(Q + (size_t)e1 * OUTW);

    int4v a[STRU], b[STRU];
#pragma unroll
    for (int s = 0; s < STRU; ++s) { a[s] = p4[s]; b[s] = q4[s]; }

#pragma unroll
    for (int s = 0; s < STRU; ++s) {
        float sum = bfdot(a[s], b[s], 0.f);
        float sig = 1.0f / (1.0f + __expf(-sum));
        float r   = sig * scale + 1.0f;
        __builtin_nontemporal_store(r, out + (size_t)s * E_ + i);
    }
}

// ---------------------------------------------------------------------------
// Fallback: fully fused per-edge (only if workspace too small).
// ---------------------------------------------------------------------------
__global__ __launch_bounds__(256) void fused_kernel(
    const float* __restrict__ x,
    const int* __restrict__ e,
    const float* __restrict__ ratio_p,
    const float* __restrict__ Wq, const float* __restrict__ bq,
    const float* __restrict__ Wv, const float* __restrict__ bv,
    float* __restrict__ out, int E_)
{
    int i = blockIdx.x * blockDim.x + threadIdx.x;
    if (i >= E_) return;

    float scale = (1.0f - ratio_p[0]) * 0.5f;
    int e0 = e[i];
    int e1 = e[E_ + i];

    const float4* __restrict__ xu  = reinterpret_cast<const float4*>(x + (size_t)e0 * HID);
    const float4* __restrict__ xv_ = reinterpret_cast<const float4*>(x + (size_t)e1 * HID);
    const float4* __restrict__ Wq4 = reinterpret_cast<const float4*>(Wq);
    const float4* __restrict__ Wv4 = reinterpret_cast<const float4*>(Wv);

#pragma unroll 1
    for (int s = 0; s < STRU; ++s) {
        float accP[NCH], accQ[NCH];
#pragma unroll
        for (int c = 0; c < NCH; ++c) { accP[c] = bq[s*NCH+c]; accQ[c] = bv[s*NCH+c]; }
        for (int kc = 0; kc < HID / 4; ++kc) {
            float4 u = xu[kc];
            float4 v = xv_[kc];
#pragma unroll
            for (int c = 0; c < NCH; ++c) {
                int o = s * NCH + c;
                accP[c] += dot4(u, Wq4[o * (HID / 4) + kc]);
                accQ[c] += dot4(v, Wv4[o * (HID / 4) + kc]);
            }
        }
        float sum = 0.0f;
#pragma unroll
        for (int c = 0; c < NCH; ++c) sum += accP[c] * accQ[c];
        float sig = 1.0f / (1.0f + __expf(-sum));
        out[(size_t)s * E_ + i] = sig * scale + 1.0f;
    }
}

extern "C" void kernel_launch(void* const* d_in, const int* in_sizes, int n_in,
                              void* d_out, int out_size, void* d_ws, size_t ws_size,
                              hipStream_t stream)
{
    const float* x     = (const float*)d_in[0];
    const int*   e     = (const int*)  d_in[1];
    const float* ratio = (const float*)d_in[2];
    const float* Wq    = (const float*)d_in[3];
    const float* bq    = (const float*)d_in[4];
    const float* Wv    = (const float*)d_in[5];
    const float* bv    = (const float*)d_in[6];
    float* out = (float*)d_out;

    int N_ = in_sizes[0] / HID;
    int E_ = in_sizes[1] / 2;

    // workspace: P (bf16 N_*32) | Q (bf16 N_*32)
    size_t need = (size_t)N_ * OUTW * 2 * sizeof(unsigned short);
    if (ws_size >= need) {
        unsigned short* P  = (unsigned short*)d_ws;
        unsigned short* Qb = P + (size_t)N_ * OUTW;

        int ntiles = (N_ + 63) / 64;
        int grid   = (ntiles + 1) / 2;   // 2 tiles per block
        proj_mfma<<<grid, 256, 0, stream>>>(x, Wq, bq, Wv, bv, P, Qb, N_);
        edge_bf16<<<(E_ + 255) / 256, 256, 0, stream>>>(e, P, Qb, ratio, out, E_);
    } else {
        fused_kernel<<<(E_ + 255) / 256, 256, 0, stream>>>(x, e, ratio, Wq, bq, Wv, bv, out, E_);
    }
}